// Round 1
// baseline (4756.495 us; speedup 1.0000x reference)
//
#include <hip/hip_runtime.h>
#include <math.h>

// Persistent-kernel implementation of the ResonatorABC scan.
// Grid: 128 WGs x 1024 threads. WG w owns features [8w, 8w+8) for ALL 128 batch
// rows -> B-reductions are WG-local. Per-row quantile (ranks 255/256/767/768)
// done by each WG for row b==blockIdx.x via exact radix select on the score
// matrix staged in global scratch. Two device-wide barriers per step.

#define T_STEPS 128
#define B_DIM   128
#define F_DIM   1024
#define NWG     128
#define NTH     1024
#define BF      (B_DIM * F_DIM)

__device__ __forceinline__ void grid_barrier(unsigned* cnt, unsigned* gen) {
  __syncthreads();
  if (threadIdx.x == 0) {
    __threadfence();  // agent-scope release: flush this XCD's L2 writes
    unsigned g = __hip_atomic_load(gen, __ATOMIC_RELAXED, __HIP_MEMORY_SCOPE_AGENT);
    unsigned a = __hip_atomic_fetch_add(cnt, 1u, __ATOMIC_ACQ_REL, __HIP_MEMORY_SCOPE_AGENT);
    if (a == (unsigned)(NWG - 1)) {
      __hip_atomic_store(cnt, 0u, __ATOMIC_RELAXED, __HIP_MEMORY_SCOPE_AGENT);
      __hip_atomic_store(gen, g + 1u, __ATOMIC_RELEASE, __HIP_MEMORY_SCOPE_AGENT);
    } else {
      while (__hip_atomic_load(gen, __ATOMIC_RELAXED, __HIP_MEMORY_SCOPE_AGENT) == g) {
        __builtin_amdgcn_s_sleep(2);
      }
    }
    __threadfence();  // agent-scope acquire: invalidate stale L1/L2 lines
  }
  __syncthreads();
}

extern "C" __global__ void __launch_bounds__(NTH)
ResonatorABC_82094004896068_kernel(
    const float* __restrict__ in_re, const float* __restrict__ in_im,
    const float* __restrict__ r_re_p, const float* __restrict__ r_im_p,
    const float* __restrict__ alpha_map, const float* __restrict__ lambda_map,
    float* __restrict__ out, float* __restrict__ ws)
{
  const int tid  = threadIdx.x;
  const int wg   = blockIdx.x;
  const int b    = tid >> 3;        // batch row of this thread
  const int fl   = tid & 7;         // feature-local index
  const int f    = (wg << 3) + fl;  // global feature
  const int wid  = tid >> 6;        // wave id (0..15)
  const int lane = tid & 63;
  const int idx  = b * F_DIM + f;

  unsigned* bar_cnt = (unsigned*)ws;
  unsigned* bar_gen = ((unsigned*)ws) + 1;
  float* tauB_g  = ws + 64;    // [128]
  float* tauC_g  = ws + 192;   // [128]
  float* score_s = ws + 1024;  // [B][F]

  __shared__ __align__(16) float pamp[16][8][4];   // wave partials: amp, amp^2, unit_re, unit_im
  __shared__ __align__(16) float pev[16][8][2];    // wave partials: evB, evC
  __shared__ unsigned histw[16 * 257];             // round-0 per-wave histograms
  __shared__ __align__(16) unsigned total[4 * 260];// merged / shared histograms (4 runs)
  __shared__ unsigned dpref[4];                    // resolved prefixes for ranks 255,256,767,768
  __shared__ unsigned drank[4];                    // remaining rank within subset

  // per-feature constants (alpha_map/lambda_map are zeros in this dataset but compute generally)
  float af = fminf(fmaxf(0.97f + 0.05f * tanhf(alpha_map[f]), 0.90f), 0.995f);
  float lf = fminf(fmaxf(0.95f + 0.05f * tanhf(lambda_map[f]), 0.90f), 0.995f);
  float rr = r_re_p[f];
  float ri = r_im_p[f];
  const float c002 = cosf(0.02f);
  const float s002 = sinf(0.02f);

  // carried state (registers). mu/var/theta/ema replicated across the 128 b-threads of f.
  float X_re = 0.f, X_im = 0.f, sA = 0.f, sB = 0.f, sC = 0.f;
  float mu = 0.f, var = 0.01f, theta = 0.1f, ema_re = 0.f, ema_im = 0.f;

  float ur = in_re[idx];
  float ui = in_im[idx];

  for (int t = 0; t < T_STEPS; ++t) {
    // ---------------- Phase 1: elementwise + B-reduced stats + score ----------------
    float Xm_re = af * X_re + ur;
    float Xm_im = af * X_im + ui;
    float amp2 = Xm_re * Xm_re + Xm_im * Xm_im;
    float amp  = sqrtf(amp2);
    float invamp = (amp > 0.f) ? (1.0f / amp) : 0.f;
    float un_re = (amp > 0.f) ? (Xm_re * invamp) : 1.0f;  // angle(0)=0 -> unit=1
    float un_im = Xm_im * invamp;
    float proj = Xm_re * rr + Xm_im * ri;                 // Re(X_mid * conj(r))
    sA = lf * sA + proj;
    out[t * BF + idx] = sA;

    float r0 = amp, r1 = amp2, r2 = un_re, r3 = un_im;
    for (int m = 8; m < 64; m <<= 1) {
      r0 += __shfl_xor(r0, m);
      r1 += __shfl_xor(r1, m);
      r2 += __shfl_xor(r2, m);
      r3 += __shfl_xor(r3, m);
    }
    if (lane < 8) { pamp[wid][lane][0]=r0; pamp[wid][lane][1]=r1; pamp[wid][lane][2]=r2; pamp[wid][lane][3]=r3; }
    __syncthreads();
    float S0=0.f, S1=0.f, S2=0.f, S3=0.f;
    #pragma unroll
    for (int w = 0; w < 16; ++w) {
      float4 p = *(const float4*)&pamp[w][fl][0];
      S0 += p.x; S1 += p.y; S2 += p.z; S3 += p.w;
    }
    float m1 = S0 * 0.0078125f;      // mean(amp)
    float m2 = S1 * 0.0078125f;      // mean(amp^2)
    mu = 0.9f * mu + 0.1f * m1;
    float vm = m2 - 2.f * mu * m1 + mu * mu;   // mean((amp-mu_new)^2)
    vm = fmaxf(vm, 0.f);
    var = 0.9f * var + 0.1f * vm;
    ema_re = 0.9f * ema_re + 0.1f * (S2 * 0.0078125f);
    ema_im = 0.9f * ema_im + 0.1f * (S3 * 0.0078125f);
    float plv = sqrtf(ema_re * ema_re + ema_im * ema_im);
    float zs = (amp - mu) / (sqrtf(var) + 1e-3f);
    float score = amp + 0.5f * fabsf(zs) + 0.5f * (1.0f - plv);
    score_s[idx] = score;            // [b][f] layout, coalesced

    grid_barrier(bar_cnt, bar_gen);

    // ---------------- Phase 2: exact radix select of ranks {255,256,767,768} for row wg ----
    float myval = score_s[wg * F_DIM + tid];
    unsigned uval = __float_as_uint(myval);  // score >= 0, so uint order == float order
    // prefetch next-step inputs; latency hidden behind select + barrier
    float ur_n = 0.f, ui_n = 0.f;
    if (t + 1 < T_STEPS) {
      ur_n = in_re[(t + 1) * BF + idx];
      ui_n = in_im[(t + 1) * BF + idx];
    }
    if (tid < 4) {
      dpref[tid] = 0u;
      drank[tid] = (tid == 0) ? 255u : (tid == 1) ? 256u : (tid == 2) ? 767u : 768u;
    }
    for (int rnd = 0; rnd < 4; ++rnd) {
      const int shift = 24 - 8 * rnd;
      const unsigned msk = rnd ? (0xFFFFFFFFu << (32 - 8 * rnd)) : 0u;
      if (rnd == 0) {
        for (int i = tid; i < 16 * 257; i += NTH) histw[i] = 0u;
      } else {
        total[tid & 1023] = 0u;               // total has 1040 entries
        if (tid < 16) total[1024 + tid] = 0u;
      }
      __syncthreads();
      unsigned p0 = dpref[0], p1 = dpref[1], p2 = dpref[2], p3 = dpref[3];
      unsigned runpref[4];
      int nruns = 1;
      runpref[0] = p0;
      if (p1 != p0) runpref[nruns++] = p1;
      if (p2 != runpref[nruns - 1]) runpref[nruns++] = p2;
      if (p3 != runpref[nruns - 1]) runpref[nruns++] = p3;
      int bin = (int)((uval >> shift) & 255u);
      if (rnd == 0) {
        atomicAdd(&histw[wid * 257 + bin], 1u);  // per-wave: kills same-address contention
      } else {
        unsigned key = uval & msk;
        int run = -1;
        if (key == runpref[0]) run = 0;
        else if (nruns > 1 && key == runpref[1]) run = 1;
        else if (nruns > 2 && key == runpref[2]) run = 2;
        else if (nruns > 3 && key == runpref[3]) run = 3;
        if (run >= 0) atomicAdd(&total[run * 260 + bin], 1u);
      }
      __syncthreads();
      if (rnd == 0) {
        if (tid < 256) {
          unsigned sh = 0u;
          #pragma unroll
          for (int w = 0; w < 16; ++w) sh += histw[w * 257 + tid];
          total[tid] = sh;
        }
        __syncthreads();
      }
      if (wid == 0) {   // wave 0: scan 256 bins per run, locate rank bins
        for (int rix = 0; rix < nruns; ++rix) {
          uint4 h = *(const uint4*)&total[rix * 260 + 4 * lane];
          unsigned scnt = h.x + h.y + h.z + h.w;
          unsigned incl = scnt;
          #pragma unroll
          for (int d = 1; d < 64; d <<= 1) {
            unsigned v = __shfl_up(incl, d);
            if (lane >= d) incl += v;
          }
          unsigned excl = incl - scnt;
          #pragma unroll
          for (int sidx = 0; sidx < 4; ++sidx) {
            unsigned sp = (sidx == 0) ? p0 : (sidx == 1) ? p1 : (sidx == 2) ? p2 : p3;
            if (sp != runpref[rix]) continue;
            unsigned k = drank[sidx];
            unsigned long long m64 = __ballot(incl > k);
            int l0 = __builtin_ctzll(m64);
            unsigned base = __shfl(excl, l0);
            unsigned h0 = __shfl(h.x, l0);
            unsigned h1 = __shfl(h.y, l0);
            unsigned h2 = __shfl(h.z, l0);
            unsigned h3 = __shfl(h.w, l0);
            int bsel; unsigned nk;
            unsigned bacc = base;
            if (k < bacc + h0) { bsel = 0; nk = k - bacc; }
            else { bacc += h0;
              if (k < bacc + h1) { bsel = 1; nk = k - bacc; }
              else { bacc += h1;
                if (k < bacc + h2) { bsel = 2; nk = k - bacc; }
                else { bacc += h2; bsel = 3; nk = k - bacc; } } }
            if (lane == 0) {
              dpref[sidx] = sp | ((unsigned)(4 * l0 + bsel) << shift);
              drank[sidx] = nk;
            }
          }
        }
      }
      __syncthreads();
    }
    if (tid == 0) {
      float s255 = __uint_as_float(dpref[0]);
      float s256 = __uint_as_float(dpref[1]);
      float s767 = __uint_as_float(dpref[2]);
      float s768 = __uint_as_float(dpref[3]);
      // quantile(score,0.75): idx 767.25 ; quantile(-score,0.75) = -(0.75*s256+0.25*s255)
      tauB_g[wg] = 0.75f * s767 + 0.25f * s768;
      tauC_g[wg] = -(0.75f * s256 + 0.25f * s255);
    }

    grid_barrier(bar_cnt, bar_gen);

    // ---------------- Phase 3: gates, s-updates, events, theta/corr, reentry ----------------
    float tb = tauB_g[b];
    float tc = tauC_g[b];
    float gB = 1.0f / (1.0f + expf(-5.0f * (score - tb)));
    float gC = 1.0f / (1.0f + expf(-5.0f * (-score - tc)));
    sB = lf * sB + proj * gB;    // Re(XB*conj(r)) = gB * proj
    sC = lf * sC + proj * gC;
    float e0 = (sB >= theta) ? 1.0f : 0.0f;   // uses carried (old) theta
    float e1 = (sC >= theta) ? 1.0f : 0.0f;
    for (int m = 8; m < 64; m <<= 1) {
      e0 += __shfl_xor(e0, m);
      e1 += __shfl_xor(e1, m);
    }
    if (lane < 8) { pev[wid][lane][0] = e0; pev[wid][lane][1] = e1; }
    __syncthreads();
    float cB = 0.f, cC = 0.f;
    #pragma unroll
    for (int w = 0; w < 16; ++w) {
      float2 p = *(const float2*)&pev[w][fl][0];
      cB += p.x; cC += p.y;
    }
    float th1 = theta + 0.01f * (cB * 0.0078125f) - 0.01f * (cC * 0.0078125f);
    theta = fminf(fmaxf(th1 - 0.01f * (th1 - 0.1f), 0.01f), 10.0f);
    // corr = any(evB) per feature; XA = X_mid*(rot + 0.1*gB*corr)
    float fac_re = 1.0f, fac_im = 0.0f;
    if (cB > 0.f) { fac_re = c002 + 0.1f * gB; fac_im = s002; }
    X_re = Xm_re * fac_re - Xm_im * fac_im;
    X_im = Xm_re * fac_im + Xm_im * fac_re;

    ur = ur_n; ui = ui_n;
  }
}

extern "C" void kernel_launch(void* const* d_in, const int* in_sizes, int n_in,
                              void* d_out, int out_size, void* d_ws, size_t ws_size,
                              hipStream_t stream) {
  const float* in_re = (const float*)d_in[0];
  const float* in_im = (const float*)d_in[1];
  const float* r_re  = (const float*)d_in[2];
  const float* r_im  = (const float*)d_in[3];
  const float* amap  = (const float*)d_in[4];
  const float* lmap  = (const float*)d_in[5];
  float* out = (float*)d_out;
  float* ws  = (float*)d_ws;
  // reset barrier counters (ws is poisoned 0xAA before timing)
  hipMemsetAsync(d_ws, 0, 8, stream);
  hipLaunchKernelGGL(ResonatorABC_82094004896068_kernel,
                     dim3(NWG), dim3(NTH), 0, stream,
                     in_re, in_im, r_re, r_im, amap, lmap, out, ws);
}

// Round 2
// 1954.122 us; speedup vs baseline: 2.4341x; 2.4341x over previous
//
#include <hip/hip_runtime.h>
#include <math.h>

// Persistent-kernel implementation of the ResonatorABC scan.
// Grid: 128 WGs x 1024 threads. WG w owns features [8w, 8w+8) for ALL 128 batch
// rows -> B-reductions are WG-local. Per-row quantile (ranks 255/256/767/768)
// done by each WG for row b==blockIdx.x via exact radix select on the score
// matrix staged in global scratch.
//
// Synchronization: NO contended fetch_add barrier, NO __threadfence (whole-L2
// writeback/invalidate). Cross-WG data (score, tau, flags) moves through the
// device coherence point via agent-scope relaxed atomics (sc1 path); barriers
// are flag-arrays (one writer per flag, parallel polling).

#define T_STEPS 128
#define B_DIM   128
#define F_DIM   1024
#define NWG     128
#define NTH     1024
#define BF      (B_DIM * F_DIM)

__device__ __forceinline__ unsigned ld_flag(const unsigned* p) {
  return __hip_atomic_load(p, __ATOMIC_RELAXED, __HIP_MEMORY_SCOPE_AGENT);
}
__device__ __forceinline__ void st_flag(unsigned* p, unsigned v) {
  __hip_atomic_store(p, v, __ATOMIC_RELAXED, __HIP_MEMORY_SCOPE_AGENT);
}
__device__ __forceinline__ float ld_coh(const float* p) {
  return __hip_atomic_load(p, __ATOMIC_RELAXED, __HIP_MEMORY_SCOPE_AGENT);
}
__device__ __forceinline__ void st_coh(float* p, float v) {
  __hip_atomic_store(p, v, __ATOMIC_RELAXED, __HIP_MEMORY_SCOPE_AGENT);
}

extern "C" __global__ void __launch_bounds__(NTH)
ResonatorABC_82094004896068_kernel(
    const float* __restrict__ in_re, const float* __restrict__ in_im,
    const float* __restrict__ r_re_p, const float* __restrict__ r_im_p,
    const float* __restrict__ alpha_map, const float* __restrict__ lambda_map,
    float* __restrict__ out, float* __restrict__ ws)
{
  const int tid  = threadIdx.x;
  const int wg   = blockIdx.x;
  const int b    = tid >> 3;        // batch row of this thread
  const int fl   = tid & 7;         // feature-local index
  const int f    = (wg << 3) + fl;  // global feature
  const int wid  = tid >> 6;        // wave id (0..15)
  const int lane = tid & 63;
  const int idx  = b * F_DIM + f;

  // ws layout (floats): flags1[128] stride4 @0, flags2[128] stride4 @512,
  // tauB[128] @1024, tauC[128] @1152, score[B][F] @2048
  unsigned* f1    = (unsigned*)ws;           // score-ready flags (stride 4)
  unsigned* f2    = ((unsigned*)ws) + 512;   // tau-ready flags (stride 4)
  float* tauB_g   = ws + 1024;
  float* tauC_g   = ws + 1152;
  float* score_s  = ws + 2048;               // [B][F]

  __shared__ __align__(16) float pamp[16][8][4];   // wave partials: amp, amp^2, unit_re, unit_im
  __shared__ __align__(16) float pev[16][8][2];    // wave partials: evB, evC
  __shared__ unsigned histw[16 * 257];             // round-0 per-wave histograms
  __shared__ __align__(16) unsigned total[4 * 260];// merged / shared histograms (4 runs)
  __shared__ unsigned dpref[4];                    // resolved prefixes for ranks 255,256,767,768
  __shared__ unsigned drank[4];                    // remaining rank within subset

  float af = fminf(fmaxf(0.97f + 0.05f * tanhf(alpha_map[f]), 0.90f), 0.995f);
  float lf = fminf(fmaxf(0.95f + 0.05f * tanhf(lambda_map[f]), 0.90f), 0.995f);
  float rr = r_re_p[f];
  float ri = r_im_p[f];
  const float c002 = cosf(0.02f);
  const float s002 = sinf(0.02f);

  // carried state (registers). mu/var/theta/ema replicated across the 128 b-threads of f.
  float X_re = 0.f, X_im = 0.f, sA = 0.f, sB = 0.f, sC = 0.f;
  float mu = 0.f, var = 0.01f, theta = 0.1f, ema_re = 0.f, ema_im = 0.f;

  float ur = in_re[idx];
  float ui = in_im[idx];

  for (int t = 0; t < T_STEPS; ++t) {
    const unsigned gen1 = 2u * t + 1u;
    const unsigned gen2 = 2u * t + 2u;

    // ---------------- Phase 1: elementwise + B-reduced stats + score ----------------
    float Xm_re = af * X_re + ur;
    float Xm_im = af * X_im + ui;
    float amp2 = Xm_re * Xm_re + Xm_im * Xm_im;
    float amp  = sqrtf(amp2);
    float invamp = (amp > 0.f) ? (1.0f / amp) : 0.f;
    float un_re = (amp > 0.f) ? (Xm_re * invamp) : 1.0f;  // angle(0)=0 -> unit=1
    float un_im = Xm_im * invamp;
    float proj = Xm_re * rr + Xm_im * ri;                 // Re(X_mid * conj(r))
    sA = lf * sA + proj;
    out[t * BF + idx] = sA;

    float r0 = amp, r1 = amp2, r2 = un_re, r3 = un_im;
    for (int m = 8; m < 64; m <<= 1) {
      r0 += __shfl_xor(r0, m);
      r1 += __shfl_xor(r1, m);
      r2 += __shfl_xor(r2, m);
      r3 += __shfl_xor(r3, m);
    }
    if (lane < 8) { pamp[wid][lane][0]=r0; pamp[wid][lane][1]=r1; pamp[wid][lane][2]=r2; pamp[wid][lane][3]=r3; }
    __syncthreads();
    float S0=0.f, S1=0.f, S2=0.f, S3=0.f;
    #pragma unroll
    for (int w = 0; w < 16; ++w) {
      float4 p = *(const float4*)&pamp[w][fl][0];
      S0 += p.x; S1 += p.y; S2 += p.z; S3 += p.w;
    }
    float m1 = S0 * 0.0078125f;      // mean(amp)
    float m2 = S1 * 0.0078125f;      // mean(amp^2)
    mu = 0.9f * mu + 0.1f * m1;
    float vm = m2 - 2.f * mu * m1 + mu * mu;   // mean((amp-mu_new)^2)
    vm = fmaxf(vm, 0.f);
    var = 0.9f * var + 0.1f * vm;
    ema_re = 0.9f * ema_re + 0.1f * (S2 * 0.0078125f);
    ema_im = 0.9f * ema_im + 0.1f * (S3 * 0.0078125f);
    float plv = sqrtf(ema_re * ema_re + ema_im * ema_im);
    float zs = (amp - mu) / (sqrtf(var) + 1e-3f);
    float score = amp + 0.5f * fabsf(zs) + 0.5f * (1.0f - plv);
    st_coh(&score_s[idx], score);    // coherent-point store, coalesced [b][f]

    // ---- barrier 1: all score stores visible (flag array, no RMW contention) ----
    __syncthreads();                 // compiler drains vmcnt(0) before s_barrier
    if (tid == 0) st_flag(&f1[wg * 4], gen1);
    if (tid < 128) {
      while (ld_flag(&f1[tid * 4]) < gen1) { __builtin_amdgcn_s_sleep(1); }
    }
    asm volatile("" ::: "memory");
    __syncthreads();

    // ---------------- Phase 2: exact radix select of ranks {255,256,767,768} for row wg ----
    float myval = ld_coh(&score_s[wg * F_DIM + tid]);
    unsigned uval = __float_as_uint(myval);  // score >= 0, so uint order == float order
    // prefetch next-step inputs (plain cached loads; latency hidden behind select)
    float ur_n = 0.f, ui_n = 0.f;
    if (t + 1 < T_STEPS) {
      ur_n = in_re[(t + 1) * BF + idx];
      ui_n = in_im[(t + 1) * BF + idx];
    }
    if (tid < 4) {
      dpref[tid] = 0u;
      drank[tid] = (tid == 0) ? 255u : (tid == 1) ? 256u : (tid == 2) ? 767u : 768u;
    }
    for (int rnd = 0; rnd < 4; ++rnd) {
      const int shift = 24 - 8 * rnd;
      const unsigned msk = rnd ? (0xFFFFFFFFu << (32 - 8 * rnd)) : 0u;
      if (rnd == 0) {
        for (int i = tid; i < 16 * 257; i += NTH) histw[i] = 0u;
      } else {
        total[tid & 1023] = 0u;               // total has 1040 entries
        if (tid < 16) total[1024 + tid] = 0u;
      }
      __syncthreads();
      unsigned p0 = dpref[0], p1 = dpref[1], p2 = dpref[2], p3 = dpref[3];
      unsigned runpref[4];
      int nruns = 1;
      runpref[0] = p0;
      if (p1 != p0) runpref[nruns++] = p1;
      if (p2 != runpref[nruns - 1]) runpref[nruns++] = p2;
      if (p3 != runpref[nruns - 1]) runpref[nruns++] = p3;
      int bin = (int)((uval >> shift) & 255u);
      if (rnd == 0) {
        atomicAdd(&histw[wid * 257 + bin], 1u);  // per-wave split: caps LDS same-address contention
      } else {
        unsigned key = uval & msk;
        int run = -1;
        if (key == runpref[0]) run = 0;
        else if (nruns > 1 && key == runpref[1]) run = 1;
        else if (nruns > 2 && key == runpref[2]) run = 2;
        else if (nruns > 3 && key == runpref[3]) run = 3;
        if (run >= 0) atomicAdd(&total[run * 260 + bin], 1u);
      }
      __syncthreads();
      if (rnd == 0) {
        if (tid < 256) {
          unsigned sh = 0u;
          #pragma unroll
          for (int w = 0; w < 16; ++w) sh += histw[w * 257 + tid];
          total[tid] = sh;
        }
        __syncthreads();
      }
      if (wid == 0) {   // wave 0: scan 256 bins per run, locate rank bins
        for (int rix = 0; rix < nruns; ++rix) {
          uint4 h = *(const uint4*)&total[rix * 260 + 4 * lane];
          unsigned scnt = h.x + h.y + h.z + h.w;
          unsigned incl = scnt;
          #pragma unroll
          for (int d = 1; d < 64; d <<= 1) {
            unsigned v = __shfl_up(incl, d);
            if (lane >= d) incl += v;
          }
          unsigned excl = incl - scnt;
          #pragma unroll
          for (int sidx = 0; sidx < 4; ++sidx) {
            unsigned sp = (sidx == 0) ? p0 : (sidx == 1) ? p1 : (sidx == 2) ? p2 : p3;
            if (sp != runpref[rix]) continue;
            unsigned k = drank[sidx];
            unsigned long long m64 = __ballot(incl > k);
            int l0 = __builtin_ctzll(m64);
            unsigned base = __shfl(excl, l0);
            unsigned h0 = __shfl(h.x, l0);
            unsigned h1 = __shfl(h.y, l0);
            unsigned h2 = __shfl(h.z, l0);
            unsigned h3 = __shfl(h.w, l0);
            int bsel; unsigned nk;
            unsigned bacc = base;
            if (k < bacc + h0) { bsel = 0; nk = k - bacc; }
            else { bacc += h0;
              if (k < bacc + h1) { bsel = 1; nk = k - bacc; }
              else { bacc += h1;
                if (k < bacc + h2) { bsel = 2; nk = k - bacc; }
                else { bacc += h2; bsel = 3; nk = k - bacc; } } }
            if (lane == 0) {
              dpref[sidx] = sp | ((unsigned)(4 * l0 + bsel) << shift);
              drank[sidx] = nk;
            }
          }
        }
      }
      __syncthreads();
    }
    if (tid == 0) {
      float s255 = __uint_as_float(dpref[0]);
      float s256 = __uint_as_float(dpref[1]);
      float s767 = __uint_as_float(dpref[2]);
      float s768 = __uint_as_float(dpref[3]);
      // quantile(score,0.75): idx 767.25 ; quantile(-score,0.75) = -(0.75*s256+0.25*s255)
      st_coh(&tauB_g[wg], 0.75f * s767 + 0.25f * s768);
      st_coh(&tauC_g[wg], -(0.75f * s256 + 0.25f * s255));
      asm volatile("s_waitcnt vmcnt(0)" ::: "memory");  // taus at coherence point before flag
      st_flag(&f2[wg * 4], gen2);
    }

    // ---- barrier 2 (per-row): wait only for own row's tau ----
    while (ld_flag(&f2[b * 4]) < gen2) { __builtin_amdgcn_s_sleep(1); }
    asm volatile("" ::: "memory");
    float tb = ld_coh(&tauB_g[b]);
    float tc = ld_coh(&tauC_g[b]);

    // ---------------- Phase 3: gates, s-updates, events, theta/corr, reentry ----------------
    float gB = 1.0f / (1.0f + expf(-5.0f * (score - tb)));
    float gC = 1.0f / (1.0f + expf(-5.0f * (-score - tc)));
    sB = lf * sB + proj * gB;    // Re(XB*conj(r)) = gB * proj
    sC = lf * sC + proj * gC;
    float e0 = (sB >= theta) ? 1.0f : 0.0f;   // uses carried (old) theta
    float e1 = (sC >= theta) ? 1.0f : 0.0f;
    for (int m = 8; m < 64; m <<= 1) {
      e0 += __shfl_xor(e0, m);
      e1 += __shfl_xor(e1, m);
    }
    if (lane < 8) { pev[wid][lane][0] = e0; pev[wid][lane][1] = e1; }
    __syncthreads();
    float cB = 0.f, cC = 0.f;
    #pragma unroll
    for (int w = 0; w < 16; ++w) {
      float2 p = *(const float2*)&pev[w][fl][0];
      cB += p.x; cC += p.y;
    }
    float th1 = theta + 0.01f * (cB * 0.0078125f) - 0.01f * (cC * 0.0078125f);
    theta = fminf(fmaxf(th1 - 0.01f * (th1 - 0.1f), 0.01f), 10.0f);
    // corr = any(evB) per feature; XA = X_mid*(rot + 0.1*gB*corr)
    float fac_re = 1.0f, fac_im = 0.0f;
    if (cB > 0.f) { fac_re = c002 + 0.1f * gB; fac_im = s002; }
    X_re = Xm_re * fac_re - Xm_im * fac_im;
    X_im = Xm_re * fac_im + Xm_im * fac_re;

    ur = ur_n; ui = ui_n;
  }
}

extern "C" void kernel_launch(void* const* d_in, const int* in_sizes, int n_in,
                              void* d_out, int out_size, void* d_ws, size_t ws_size,
                              hipStream_t stream) {
  const float* in_re = (const float*)d_in[0];
  const float* in_im = (const float*)d_in[1];
  const float* r_re  = (const float*)d_in[2];
  const float* r_im  = (const float*)d_in[3];
  const float* amap  = (const float*)d_in[4];
  const float* lmap  = (const float*)d_in[5];
  float* out = (float*)d_out;
  float* ws  = (float*)d_ws;
  // zero the flag arrays (ws is poisoned 0xAA before timing; flags must start < gen1)
  hipMemsetAsync(d_ws, 0, 4096, stream);
  hipLaunchKernelGGL(ResonatorABC_82094004896068_kernel,
                     dim3(NWG), dim3(NTH), 0, stream,
                     in_re, in_im, r_re, r_im, amap, lmap, out, ws);
}

// Round 3
// 1890.326 us; speedup vs baseline: 2.5162x; 1.0337x over previous
//
#include <hip/hip_runtime.h>
#include <math.h>

// Persistent-kernel ResonatorABC scan — TAGGED-DATAFLOW version (no grid barriers).
// Grid: 128 WGs x 1024 threads. WG w owns features [8w,8w+8) for ALL 128 rows
// (B-reductions WG-local) and performs the exact radix select for row b==wg.
// Cross-WG words (score, tauB, tauC) are 64-bit {tag=t+1 | value} atomics at
// agent scope; every consumer polls exactly the words it needs. Causality:
// score(t+1)[b][f] is stored by the same thread that polled tau(t)[b], and
// tau(t+1)[b] requires all score(t+1)[b][*] -> no overwrite before last read.

#define T_STEPS 128
#define B_DIM   128
#define F_DIM   1024
#define NWG     128
#define NTH     1024
#define BF      (B_DIM * F_DIM)

typedef unsigned long long ull;

__device__ __forceinline__ ull ld64(const ull* p) {
  return __hip_atomic_load(p, __ATOMIC_RELAXED, __HIP_MEMORY_SCOPE_AGENT);
}
__device__ __forceinline__ void st64(ull* p, ull v) {
  __hip_atomic_store(p, v, __ATOMIC_RELAXED, __HIP_MEMORY_SCOPE_AGENT);
}

extern "C" __global__ void __launch_bounds__(NTH)
ResonatorABC_82094004896068_kernel(
    const float* __restrict__ in_re, const float* __restrict__ in_im,
    const float* __restrict__ r_re_p, const float* __restrict__ r_im_p,
    const float* __restrict__ alpha_map, const float* __restrict__ lambda_map,
    float* __restrict__ out, ull* __restrict__ ws)
{
  const int tid  = threadIdx.x;
  const int wg   = blockIdx.x;
  const int b    = tid >> 3;        // batch row of this thread
  const int fl   = tid & 7;         // feature-local index
  const int f    = (wg << 3) + fl;  // global feature
  const int wid  = tid >> 6;        // wave id (0..15)
  const int lane = tid & 63;
  const int idx  = b * F_DIM + f;

  ull* score64 = ws;                // [B][F] {tag|score_bits}
  ull* tauB64  = ws + BF;           // [128]  {tag|tauB_bits}
  ull* tauC64  = ws + BF + 128;     // [128]  {tag|tauC_bits}

  __shared__ __align__(16) float pamp[16][8][4];   // wave partials: amp, amp^2, unit_re, unit_im
  __shared__ __align__(16) float pev[16][8][2];    // wave partials: evB, evC
  __shared__ unsigned histw[16 * 257];             // round-0 per-wave histograms
  __shared__ __align__(16) unsigned total[4 * 260];// merged / shared histograms (4 runs)
  __shared__ unsigned dpref[4];                    // resolved prefixes for ranks 255,256,767,768
  __shared__ unsigned drank[4];                    // remaining rank within subset

  float af = fminf(fmaxf(0.97f + 0.05f * tanhf(alpha_map[f]), 0.90f), 0.995f);
  float lf = fminf(fmaxf(0.95f + 0.05f * tanhf(lambda_map[f]), 0.90f), 0.995f);
  float rr = r_re_p[f];
  float ri = r_im_p[f];
  const float c002 = cosf(0.02f);
  const float s002 = sinf(0.02f);

  // carried state (registers). mu/var/theta/ema replicated across the 128 b-threads of f.
  float X_re = 0.f, X_im = 0.f, sA = 0.f, sB = 0.f, sC = 0.f;
  float mu = 0.f, var = 0.01f, theta = 0.1f, ema_re = 0.f, ema_im = 0.f;

  float ur = in_re[idx];
  float ui = in_im[idx];

  for (int t = 0; t < T_STEPS; ++t) {
    const ull want = (ull)(t + 1);

    // ---------------- Phase 1: elementwise + B-reduced stats + score ----------------
    float Xm_re = af * X_re + ur;
    float Xm_im = af * X_im + ui;
    float amp2 = Xm_re * Xm_re + Xm_im * Xm_im;
    float amp  = sqrtf(amp2);
    float invamp = (amp > 0.f) ? (1.0f / amp) : 0.f;
    float un_re = (amp > 0.f) ? (Xm_re * invamp) : 1.0f;  // angle(0)=0 -> unit=1
    float un_im = Xm_im * invamp;
    float proj = Xm_re * rr + Xm_im * ri;                 // Re(X_mid * conj(r))
    sA = lf * sA + proj;
    out[t * BF + idx] = sA;

    float r0 = amp, r1 = amp2, r2 = un_re, r3 = un_im;
    for (int m = 8; m < 64; m <<= 1) {
      r0 += __shfl_xor(r0, m);
      r1 += __shfl_xor(r1, m);
      r2 += __shfl_xor(r2, m);
      r3 += __shfl_xor(r3, m);
    }
    if (lane < 8) { pamp[wid][lane][0]=r0; pamp[wid][lane][1]=r1; pamp[wid][lane][2]=r2; pamp[wid][lane][3]=r3; }
    __syncthreads();
    float S0=0.f, S1=0.f, S2=0.f, S3=0.f;
    #pragma unroll
    for (int w = 0; w < 16; ++w) {
      float4 p = *(const float4*)&pamp[w][fl][0];
      S0 += p.x; S1 += p.y; S2 += p.z; S3 += p.w;
    }
    float m1 = S0 * 0.0078125f;      // mean(amp)
    float m2 = S1 * 0.0078125f;      // mean(amp^2)
    mu = 0.9f * mu + 0.1f * m1;
    float vm = m2 - 2.f * mu * m1 + mu * mu;   // mean((amp-mu_new)^2)
    vm = fmaxf(vm, 0.f);
    var = 0.9f * var + 0.1f * vm;
    ema_re = 0.9f * ema_re + 0.1f * (S2 * 0.0078125f);
    ema_im = 0.9f * ema_im + 0.1f * (S3 * 0.0078125f);
    float plv = sqrtf(ema_re * ema_re + ema_im * ema_im);
    float zs = (amp - mu) / (sqrtf(var) + 1e-3f);
    float score = amp + 0.5f * fabsf(zs) + 0.5f * (1.0f - plv);
    // publish tagged score: one 64B line per (row, writer-WG) -> single writer per line
    st64(&score64[idx], (want << 32) | (ull)__float_as_uint(score));

    // ---------------- Phase 2: poll own select element, exact radix select ----------------
    ull v = ld64(&score64[wg * F_DIM + tid]);
    while ((v >> 32) != want) { __builtin_amdgcn_s_sleep(1); v = ld64(&score64[wg * F_DIM + tid]); }
    unsigned uval = (unsigned)v;             // score >= 0: uint order == float order

    // prefetch next-step inputs (plain cached loads; latency hidden behind select)
    float ur_n = 0.f, ui_n = 0.f;
    if (t + 1 < T_STEPS) {
      ur_n = in_re[(t + 1) * BF + idx];
      ui_n = in_im[(t + 1) * BF + idx];
    }
    if (tid < 4) {
      dpref[tid] = 0u;
      drank[tid] = (tid == 0) ? 255u : (tid == 1) ? 256u : (tid == 2) ? 767u : 768u;
    }
    for (int rnd = 0; rnd < 4; ++rnd) {
      const int shift = 24 - 8 * rnd;
      const unsigned msk = rnd ? (0xFFFFFFFFu << (32 - 8 * rnd)) : 0u;
      if (rnd == 0) {
        for (int i = tid; i < 16 * 257; i += NTH) histw[i] = 0u;
      } else {
        total[tid & 1023] = 0u;               // total has 1040 entries
        if (tid < 16) total[1024 + tid] = 0u;
      }
      __syncthreads();
      unsigned p0 = dpref[0], p1 = dpref[1], p2 = dpref[2], p3 = dpref[3];
      unsigned runpref[4];
      int nruns = 1;
      runpref[0] = p0;
      if (p1 != p0) runpref[nruns++] = p1;
      if (p2 != runpref[nruns - 1]) runpref[nruns++] = p2;
      if (p3 != runpref[nruns - 1]) runpref[nruns++] = p3;
      int bin = (int)((uval >> shift) & 255u);
      if (rnd == 0) {
        atomicAdd(&histw[wid * 257 + bin], 1u);  // per-wave split: caps LDS same-address contention
      } else {
        unsigned key = uval & msk;
        int run = -1;
        if (key == runpref[0]) run = 0;
        else if (nruns > 1 && key == runpref[1]) run = 1;
        else if (nruns > 2 && key == runpref[2]) run = 2;
        else if (nruns > 3 && key == runpref[3]) run = 3;
        if (run >= 0) atomicAdd(&total[run * 260 + bin], 1u);
      }
      __syncthreads();
      if (rnd == 0) {
        if (tid < 256) {
          unsigned sh = 0u;
          #pragma unroll
          for (int w = 0; w < 16; ++w) sh += histw[w * 257 + tid];
          total[tid] = sh;
        }
        __syncthreads();
      }
      if (wid == 0) {   // wave 0: scan 256 bins per run, locate rank bins
        for (int rix = 0; rix < nruns; ++rix) {
          uint4 h = *(const uint4*)&total[rix * 260 + 4 * lane];
          unsigned scnt = h.x + h.y + h.z + h.w;
          unsigned incl = scnt;
          #pragma unroll
          for (int d = 1; d < 64; d <<= 1) {
            unsigned vv = __shfl_up(incl, d);
            if (lane >= d) incl += vv;
          }
          unsigned excl = incl - scnt;
          #pragma unroll
          for (int sidx = 0; sidx < 4; ++sidx) {
            unsigned sp = (sidx == 0) ? p0 : (sidx == 1) ? p1 : (sidx == 2) ? p2 : p3;
            if (sp != runpref[rix]) continue;
            unsigned k = drank[sidx];
            unsigned long long m64 = __ballot(incl > k);
            int l0 = __builtin_ctzll(m64);
            unsigned base = __shfl(excl, l0);
            unsigned h0 = __shfl(h.x, l0);
            unsigned h1 = __shfl(h.y, l0);
            unsigned h2 = __shfl(h.z, l0);
            unsigned h3 = __shfl(h.w, l0);
            int bsel; unsigned nk;
            unsigned bacc = base;
            if (k < bacc + h0) { bsel = 0; nk = k - bacc; }
            else { bacc += h0;
              if (k < bacc + h1) { bsel = 1; nk = k - bacc; }
              else { bacc += h1;
                if (k < bacc + h2) { bsel = 2; nk = k - bacc; }
                else { bacc += h2; bsel = 3; nk = k - bacc; } } }
            if (lane == 0) {
              dpref[sidx] = sp | ((unsigned)(4 * l0 + bsel) << shift);
              drank[sidx] = nk;
            }
          }
        }
      }
      __syncthreads();
    }
    if (tid == 0) {
      float s255 = __uint_as_float(dpref[0]);
      float s256 = __uint_as_float(dpref[1]);
      float s767 = __uint_as_float(dpref[2]);
      float s768 = __uint_as_float(dpref[3]);
      // quantile(score,0.75): idx 767.25 ; quantile(-score,0.75) = -(0.75*s256+0.25*s255)
      float tb = 0.75f * s767 + 0.25f * s768;
      float tc = -(0.75f * s256 + 0.25f * s255);
      st64(&tauB64[wg], (want << 32) | (ull)__float_as_uint(tb));
      st64(&tauC64[wg], (want << 32) | (ull)__float_as_uint(tc));
    }

    // ---------------- Phase 3: poll own row's taus; gates, s-updates, theta, reentry ----
    ull vb = ld64(&tauB64[b]);
    ull vc = ld64(&tauC64[b]);
    while ((vb >> 32) != want || (vc >> 32) != want) {
      __builtin_amdgcn_s_sleep(1);
      vb = ld64(&tauB64[b]);
      vc = ld64(&tauC64[b]);
    }
    float tb = __uint_as_float((unsigned)vb);
    float tc = __uint_as_float((unsigned)vc);

    float gB = 1.0f / (1.0f + expf(-5.0f * (score - tb)));
    float gC = 1.0f / (1.0f + expf(-5.0f * (-score - tc)));
    sB = lf * sB + proj * gB;    // Re(XB*conj(r)) = gB * proj
    sC = lf * sC + proj * gC;
    float e0 = (sB >= theta) ? 1.0f : 0.0f;   // uses carried (old) theta
    float e1 = (sC >= theta) ? 1.0f : 0.0f;
    for (int m = 8; m < 64; m <<= 1) {
      e0 += __shfl_xor(e0, m);
      e1 += __shfl_xor(e1, m);
    }
    if (lane < 8) { pev[wid][lane][0] = e0; pev[wid][lane][1] = e1; }
    __syncthreads();
    float cB = 0.f, cC = 0.f;
    #pragma unroll
    for (int w = 0; w < 16; ++w) {
      float2 p = *(const float2*)&pev[w][fl][0];
      cB += p.x; cC += p.y;
    }
    float th1 = theta + 0.01f * (cB * 0.0078125f) - 0.01f * (cC * 0.0078125f);
    theta = fminf(fmaxf(th1 - 0.01f * (th1 - 0.1f), 0.01f), 10.0f);
    // corr = any(evB) per feature; XA = X_mid*(rot + 0.1*gB*corr)
    float fac_re = 1.0f, fac_im = 0.0f;
    if (cB > 0.f) { fac_re = c002 + 0.1f * gB; fac_im = s002; }
    X_re = Xm_re * fac_re - Xm_im * fac_im;
    X_im = Xm_re * fac_im + Xm_im * fac_re;

    ur = ur_n; ui = ui_n;
  }
}

extern "C" void kernel_launch(void* const* d_in, const int* in_sizes, int n_in,
                              void* d_out, int out_size, void* d_ws, size_t ws_size,
                              hipStream_t stream) {
  const float* in_re = (const float*)d_in[0];
  const float* in_im = (const float*)d_in[1];
  const float* r_re  = (const float*)d_in[2];
  const float* r_im  = (const float*)d_in[3];
  const float* amap  = (const float*)d_in[4];
  const float* lmap  = (const float*)d_in[5];
  float* out = (float*)d_out;
  ull* ws = (ull*)d_ws;
  // zero all tag words so no stale/garbage tag can match (deterministic per launch)
  hipMemsetAsync(d_ws, 0, (size_t)(BF + 256) * 8, stream);
  hipLaunchKernelGGL(ResonatorABC_82094004896068_kernel,
                     dim3(NWG), dim3(NTH), 0, stream,
                     in_re, in_im, r_re, r_im, amap, lmap, out, ws);
}